// Round 1
// baseline (1219.150 us; speedup 1.0000x reference)
//
#include <hip/hip_runtime.h>
#include <cstdint>
#include <cstddef>

typedef unsigned short u16;
using bf16x8  = __attribute__((ext_vector_type(8))) short;
using floatx4 = __attribute__((ext_vector_type(4))) float;

// ---------- helpers ----------
__device__ __forceinline__ u16 f2bf(float f) {
    union { float f; unsigned u; } v; v.f = f;
    unsigned r = v.u + 0x7fffu + ((v.u >> 16) & 1u);   // RNE
    return (u16)(r >> 16);
}
__device__ __forceinline__ float bf2f(u16 h) {
    union { unsigned u; float f; } v; v.u = ((unsigned)h) << 16; return v.f;
}
__device__ __forceinline__ floatx4 mfma16(bf16x8 a, bf16x8 b, floatx4 c) {
    return __builtin_amdgcn_mfma_f32_16x16x32_bf16(a, b, c, 0, 0, 0);
}
using gptr_t = const __attribute__((address_space(1))) unsigned int*;
using lptr_t = __attribute__((address_space(3))) unsigned int*;
__device__ __forceinline__ void lds16(const void* g, void* l) {
    // async global->LDS, 16B/lane; LDS dest = wave-uniform base + lane*16
    __builtin_amdgcn_global_load_lds((gptr_t)g, (lptr_t)l, 16, 0, 0);
}

// ---------- 1. convert x f32 -> bf16 ----------
__global__ __launch_bounds__(256) void cvt_x(const float* __restrict__ x, u16* __restrict__ xb) {
    size_t i = ((size_t)blockIdx.x * 256 + threadIdx.x) * 4;
    float4 v = *(const float4*)&x[i];
    u16 r0 = f2bf(v.x), r1 = f2bf(v.y), r2 = f2bf(v.z), r3 = f2bf(v.w);
    ushort4 r; r.x = r0; r.y = r1; r.z = r2; r.w = r3;
    *(ushort4*)&xb[i] = r;
}

// ---------- 2. transpose+convert weight f32 [2048][2048] -> bf16 [n][k] ----------
__global__ __launch_bounds__(256) void transpose_w(const float* __restrict__ in, u16* __restrict__ out) {
    __shared__ float t[64][65];
    int k0 = blockIdx.x * 64, n0 = blockIdx.y * 64;
    int tx = threadIdx.x, ty = threadIdx.y;   // (64,4)
#pragma unroll
    for (int i = 0; i < 16; ++i) {
        int r = i * 4 + ty;
        t[r][tx] = in[(size_t)(k0 + r) * 2048 + n0 + tx];
    }
    __syncthreads();
#pragma unroll
    for (int i = 0; i < 16; ++i) {
        int r = i * 4 + ty;
        out[(size_t)(n0 + r) * 2048 + k0 + tx] = f2bf(t[tx][r]);
    }
}

// ---------- 3. main GEMM (A[m][k] bf16, B^T[n][k] bf16), 128x128 tile, BK=64 ----------
// MODE 0: QKV projection, scatter bf16 into Q/K/V [b][h][s][d]
// MODE 1: output projection, f32 into d_out [m][n]
template <int MODE>
__global__ __launch_bounds__(256) void gemm_bt(const u16* __restrict__ A, const u16* __restrict__ B,
                                               u16* __restrict__ Qo, u16* __restrict__ Ko, u16* __restrict__ Vo,
                                               float* __restrict__ Co) {
    __shared__ __align__(16) u16 As[128 * 64];
    __shared__ __align__(16) u16 Bs[128 * 64];
    const int m0 = blockIdx.y << 7;
    const int n0 = blockIdx.x << 7;
    const int tid = threadIdx.x;
    const int w = tid >> 6, lane = tid & 63;
    const int wm = w >> 1, wn = w & 1;       // 2x2 wave grid, each wave 64x64
    const int m16 = lane & 15, q4 = lane >> 4;

    floatx4 acc[4][4];
#pragma unroll
    for (int r = 0; r < 4; ++r)
#pragma unroll
        for (int c = 0; c < 4; ++c) acc[r][c] = (floatx4)0.0f;

    // staging: each wave moves 32 rows of A-tile and B-tile; 8 rows per global_load_lds
    const u16* Abase = A + (size_t)(m0 + w * 32 + (lane >> 3)) * 2048 + (lane & 7) * 8;
    const u16* Bbase = B + (size_t)(n0 + w * 32 + (lane >> 3)) * 2048 + (lane & 7) * 8;
    u16* lA = As + (w * 32) * 64;
    u16* lB = Bs + (w * 32) * 64;

    for (int kt = 0; kt < 32; ++kt) {
        __syncthreads();                      // protect LDS reuse
        const u16* ga = Abase + kt * 64;
        const u16* gb = Bbase + kt * 64;
#pragma unroll
        for (int t = 0; t < 4; ++t) {
            lds16(ga + (size_t)t * 8 * 2048, lA + t * 8 * 64);
            lds16(gb + (size_t)t * 8 * 2048, lB + t * 8 * 64);
        }
        __syncthreads();                      // vmcnt(0) drain + barrier
#pragma unroll
        for (int kk = 0; kk < 2; ++kk) {
            bf16x8 af[4], bfr[4];
#pragma unroll
            for (int r = 0; r < 4; ++r)
                af[r] = *(const bf16x8*)&As[(wm * 64 + r * 16 + m16) * 64 + kk * 32 + q4 * 8];
#pragma unroll
            for (int c = 0; c < 4; ++c)
                bfr[c] = *(const bf16x8*)&Bs[(wn * 64 + c * 16 + m16) * 64 + kk * 32 + q4 * 8];
#pragma unroll
            for (int r = 0; r < 4; ++r)
#pragma unroll
                for (int c = 0; c < 4; ++c)
                    acc[r][c] = mfma16(af[r], bfr[c], acc[r][c]);
        }
    }

    // epilogue: C/D layout col = lane&15, row = q4*4 + i  [measured m89/m91]
    if (MODE == 0) {
        const int which = n0 >> 11;           // 0=Q 1=K 2=V (N tiles of 128 == one head)
        const int h = (n0 >> 7) & 15;
        u16* dst = (which == 0) ? Qo : ((which == 1) ? Ko : Vo);
#pragma unroll
        for (int r = 0; r < 4; ++r) {
#pragma unroll
            for (int c = 0; c < 4; ++c) {
                int d = wn * 64 + c * 16 + m16;
                int mbase = m0 + wm * 64 + r * 16 + q4 * 4;
#pragma unroll
                for (int i = 0; i < 4; ++i) {
                    int mm = mbase + i;
                    int b = mm >> 11, s = mm & 2047;
                    dst[((size_t)((b * 16 + h) * 2048 + s) << 7) + d] = f2bf(acc[r][c][i]);
                }
            }
        }
    } else {
#pragma unroll
        for (int r = 0; r < 4; ++r) {
#pragma unroll
            for (int c = 0; c < 4; ++c) {
                int n = n0 + wn * 64 + c * 16 + m16;
                int mbase = m0 + wm * 64 + r * 16 + q4 * 4;
#pragma unroll
                for (int i = 0; i < 4; ++i)
                    Co[(size_t)(mbase + i) * 2048 + n] = acc[r][c][i];
            }
        }
    }
}

// ---------- 4. RoPE in place on Q,K [b][h][s][128] ----------
__global__ __launch_bounds__(256) void rope_qk(u16* __restrict__ Q, u16* __restrict__ K,
                                               const float* __restrict__ cosb, const float* __restrict__ sinb) {
    int t = blockIdx.x * 256 + threadIdx.x;   // over B*H*S*64 = 8388608
    int d = t & 63;
    int row = t >> 6;                         // (b*16+h)*2048 + s
    int s = row & 2047;
    float c = cosb[s * 64 + d], sn = sinb[s * 64 + d];
    size_t base = (size_t)row * 128;
    float q0 = bf2f(Q[base + d]), q1 = bf2f(Q[base + 64 + d]);
    Q[base + d]      = f2bf(q0 * c - q1 * sn);
    Q[base + 64 + d] = f2bf(q1 * c + q0 * sn);
    float k0 = bf2f(K[base + d]), k1 = bf2f(K[base + 64 + d]);
    K[base + d]      = f2bf(k0 * c - k1 * sn);
    K[base + 64 + d] = f2bf(k1 * c + k0 * sn);
}

// ---------- 5. transpose V [b,h][2048][128] -> V^T [b,h][128][2048] (bf16) ----------
__global__ __launch_bounds__(256) void transpose_v(const u16* __restrict__ V, u16* __restrict__ VT) {
    __shared__ u16 t[64][65];
    int bh = blockIdx.z;
    const u16* in = V + (size_t)bh * 2048 * 128;
    u16* out = VT + (size_t)bh * 128 * 2048;
    int s0 = blockIdx.x * 64, d0 = blockIdx.y * 64;
    int tx = threadIdx.x, ty = threadIdx.y;
#pragma unroll
    for (int i = 0; i < 16; ++i) {
        int r = i * 4 + ty;
        t[r][tx] = in[(size_t)(s0 + r) * 128 + d0 + tx];
    }
    __syncthreads();
#pragma unroll
    for (int i = 0; i < 16; ++i) {
        int r = i * 4 + ty;
        out[(size_t)(d0 + r) * 2048 + s0 + tx] = t[tx][r];
    }
}

// ---------- 6. causal flash attention: BQ=128 (block), BK=64, HD=128 ----------
// Q,K: [b,h,s,128] bf16 (post-RoPE), VT: [b,h,128,s] bf16, AO: [b,s,h*128+d] bf16
__global__ __launch_bounds__(256) void attn_kernel(const u16* __restrict__ Q, const u16* __restrict__ K,
                                                   const u16* __restrict__ VT, u16* __restrict__ AO) {
    __shared__ __align__(16) u16 ks[64 * 136];    // K-tile  [kcol 64][d 128], pad->136
    __shared__ __align__(16) u16 vts[128 * 72];   // V^T-tile [d 128][s 64], pad->72
    __shared__ __align__(16) u16 ps[128 * 72];    // P tile  [q 128][kcol 64], pad->72
    const int iq = blockIdx.x, bh = blockIdx.y;
    const int b = bh >> 4, h = bh & 15;
    const u16* Qg = Q  + (size_t)bh * (2048 * 128);
    const u16* Kg = K  + (size_t)bh * (2048 * 128);
    const u16* Vg = VT + (size_t)bh * (128 * 2048);
    const int tid = threadIdx.x, w = tid >> 6, lane = tid & 63;
    const int m16 = lane & 15, q4 = lane >> 4;

    // Q fragments live in registers: wave w owns q-rows [w*32, w*32+32)
    bf16x8 qf[2][4];
#pragma unroll
    for (int rm = 0; rm < 2; ++rm)
#pragma unroll
        for (int kk = 0; kk < 4; ++kk)
            qf[rm][kk] = *(const bf16x8*)&Qg[(size_t)(iq * 128 + w * 32 + rm * 16 + m16) * 128 + kk * 32 + q4 * 8];

    floatx4 o[2][8];
#pragma unroll
    for (int rm = 0; rm < 2; ++rm)
#pragma unroll
        for (int c = 0; c < 8; ++c) o[rm][c] = (floatx4)0.0f;
    float mrow[2][4], lrow[2][4];
#pragma unroll
    for (int rm = 0; rm < 2; ++rm)
#pragma unroll
        for (int i = 0; i < 4; ++i) { mrow[rm][i] = -1e30f; lrow[rm][i] = 0.0f; }

    const float kscale = 1.44269504088896341f * 0.08838834764831845f;  // log2(e)/sqrt(128)
    const int jn = 2 * iq + 2;
    for (int j = 0; j < jn; ++j) {
        __syncthreads();
        // stage K tile: 64 rows x 128 d
        for (int u = tid; u < 1024; u += 256) {
            int row = u >> 4, c16 = u & 15;
            *(uint4*)&ks[row * 136 + c16 * 8] = *(const uint4*)&Kg[(size_t)(j * 64 + row) * 128 + c16 * 8];
        }
        // stage V^T tile: 128 d-rows x 64 s
        for (int u = tid; u < 1024; u += 256) {
            int row = u >> 3, c8 = u & 7;
            *(uint4*)&vts[row * 72 + c8 * 8] = *(const uint4*)&Vg[(size_t)row * 2048 + j * 64 + c8 * 8];
        }
        __syncthreads();

        // S = Q K^T  (wave computes its 32 rows x 64 cols)
        floatx4 sacc[2][4];
#pragma unroll
        for (int rm = 0; rm < 2; ++rm)
#pragma unroll
            for (int c = 0; c < 4; ++c) sacc[rm][c] = (floatx4)0.0f;
#pragma unroll
        for (int kk = 0; kk < 4; ++kk) {
            bf16x8 kb[4];
#pragma unroll
            for (int c = 0; c < 4; ++c)
                kb[c] = *(const bf16x8*)&ks[(c * 16 + m16) * 136 + kk * 32 + q4 * 8];
#pragma unroll
            for (int rm = 0; rm < 2; ++rm)
#pragma unroll
                for (int c = 0; c < 4; ++c)
                    sacc[rm][c] = mfma16(qf[rm][kk], kb[c], sacc[rm][c]);
        }

        const bool domask = (j >= 2 * iq);
#pragma unroll
        for (int rm = 0; rm < 2; ++rm) {
            float rmax[4] = {-1e30f, -1e30f, -1e30f, -1e30f};
#pragma unroll
            for (int c = 0; c < 4; ++c)
#pragma unroll
                for (int i = 0; i < 4; ++i) {
                    float s = sacc[rm][c][i] * kscale;
                    if (domask) {
                        int col = j * 64 + c * 16 + m16;
                        int row = iq * 128 + w * 32 + rm * 16 + q4 * 4 + i;
                        if (col > row) s = -1e30f;
                    }
                    sacc[rm][c][i] = s;
                    rmax[i] = fmaxf(rmax[i], s);
                }
#pragma unroll
            for (int d = 1; d < 16; d <<= 1)
#pragma unroll
                for (int i = 0; i < 4; ++i)
                    rmax[i] = fmaxf(rmax[i], __shfl_xor(rmax[i], d));
            float mnew[4], alpha[4], rsum[4];
#pragma unroll
            for (int i = 0; i < 4; ++i) {
                mnew[i] = fmaxf(mrow[rm][i], rmax[i]);
                alpha[i] = exp2f(mrow[rm][i] - mnew[i]);
                mrow[rm][i] = mnew[i];
                rsum[i] = 0.0f;
            }
#pragma unroll
            for (int c = 0; c < 4; ++c)
#pragma unroll
                for (int i = 0; i < 4; ++i) {
                    float p = exp2f(sacc[rm][c][i] - mnew[i]);
                    rsum[i] += p;
                    ps[(w * 32 + rm * 16 + q4 * 4 + i) * 72 + c * 16 + m16] = f2bf(p);
                }
#pragma unroll
            for (int d = 1; d < 16; d <<= 1)
#pragma unroll
                for (int i = 0; i < 4; ++i)
                    rsum[i] += __shfl_xor(rsum[i], d);
#pragma unroll
            for (int i = 0; i < 4; ++i)
                lrow[rm][i] = lrow[rm][i] * alpha[i] + rsum[i];
#pragma unroll
            for (int c = 0; c < 8; ++c)
#pragma unroll
                for (int i = 0; i < 4; ++i)
                    o[rm][c][i] *= alpha[i];
        }
        __syncthreads();   // P visible (safety) before A-layout reads

        // O += P V   (contraction over the 64 k-cols)
#pragma unroll
        for (int kk = 0; kk < 2; ++kk) {
            bf16x8 pa[2], vb[8];
#pragma unroll
            for (int rm = 0; rm < 2; ++rm)
                pa[rm] = *(const bf16x8*)&ps[(w * 32 + rm * 16 + m16) * 72 + kk * 32 + q4 * 8];
#pragma unroll
            for (int c = 0; c < 8; ++c)
                vb[c] = *(const bf16x8*)&vts[(c * 16 + m16) * 72 + kk * 32 + q4 * 8];
#pragma unroll
            for (int rm = 0; rm < 2; ++rm)
#pragma unroll
                for (int c = 0; c < 8; ++c)
                    o[rm][c] = mfma16(pa[rm], vb[c], o[rm][c]);
        }
    }

    // write AO [b][s][h*128+d]
#pragma unroll
    for (int rm = 0; rm < 2; ++rm) {
        float inv[4];
#pragma unroll
        for (int i = 0; i < 4; ++i) inv[i] = 1.0f / lrow[rm][i];
#pragma unroll
        for (int c = 0; c < 8; ++c)
#pragma unroll
            for (int i = 0; i < 4; ++i) {
                int s = iq * 128 + w * 32 + rm * 16 + q4 * 4 + i;
                int d = c * 16 + m16;
                AO[((size_t)(b * 2048 + s)) * 2048 + h * 128 + d] = f2bf(o[rm][c][i] * inv[i]);
            }
    }
}

// ---------- launch ----------
extern "C" void kernel_launch(void* const* d_in, const int* in_sizes, int n_in,
                              void* d_out, int out_size, void* d_ws, size_t ws_size,
                              hipStream_t stream) {
    const float* x    = (const float*)d_in[0];
    const float* wq   = (const float*)d_in[1];
    const float* wk   = (const float*)d_in[2];
    const float* wv   = (const float*)d_in[3];
    const float* wo   = (const float*)d_in[4];
    const float* cosb = (const float*)d_in[5];
    const float* sinb = (const float*)d_in[6];
    float* out = (float*)d_out;

    char* ws = (char*)d_ws;
    // layout (bytes): xb/AO 33.5M | wqkvb 25.2M | wob 8.4M | Q 33.5M | K 33.5M | V 33.5M | VT 33.5M = 192 MiB
    u16* xb    = (u16*)(ws);
    u16* AO    = xb;                                  // alias: xb dead after QKV GEMM, AO written later
    u16* wqkvb = (u16*)(ws + 33554432);
    u16* wob   = (u16*)(ws + 58720256);
    u16* Qb    = (u16*)(ws + 67108864);
    u16* Kb    = (u16*)(ws + 100663296);
    u16* Vb    = (u16*)(ws + 134217728);
    u16* Vtb   = (u16*)(ws + 167772160);

    cvt_x<<<16384, 256, 0, stream>>>(x, xb);
    transpose_w<<<dim3(32, 32), dim3(64, 4), 0, stream>>>(wq, wqkvb);
    transpose_w<<<dim3(32, 32), dim3(64, 4), 0, stream>>>(wk, wqkvb + (size_t)2048 * 2048);
    transpose_w<<<dim3(32, 32), dim3(64, 4), 0, stream>>>(wv, wqkvb + (size_t)2 * 2048 * 2048);
    transpose_w<<<dim3(32, 32), dim3(64, 4), 0, stream>>>(wo, wob);

    gemm_bt<0><<<dim3(48, 64), 256, 0, stream>>>(xb, wqkvb, Qb, Kb, Vb, nullptr);
    rope_qk<<<32768, 256, 0, stream>>>(Qb, Kb, cosb, sinb);
    transpose_v<<<dim3(32, 2, 64), dim3(64, 4), 0, stream>>>(Vb, Vtb);
    attn_kernel<<<dim3(16, 64), 256, 0, stream>>>(Qb, Kb, Vtb, AO);
    gemm_bt<1><<<dim3(16, 64), 256, 0, stream>>>(AO, wob, nullptr, nullptr, nullptr, out);
}

// Round 2
// 652.461 us; speedup vs baseline: 1.8685x; 1.8685x over previous
//
#include <hip/hip_runtime.h>
#include <cstdint>
#include <cstddef>

typedef unsigned short u16;
using bf16x8  = __attribute__((ext_vector_type(8))) short;
using floatx4 = __attribute__((ext_vector_type(4))) float;

// ---------- helpers ----------
__device__ __forceinline__ u16 f2bf(float f) {
    union { float f; unsigned u; } v; v.f = f;
    unsigned r = v.u + 0x7fffu + ((v.u >> 16) & 1u);   // RNE
    return (u16)(r >> 16);
}
__device__ __forceinline__ float bf2f(u16 h) {
    union { unsigned u; float f; } v; v.u = ((unsigned)h) << 16; return v.f;
}
__device__ __forceinline__ floatx4 mfma16(bf16x8 a, bf16x8 b, floatx4 c) {
    return __builtin_amdgcn_mfma_f32_16x16x32_bf16(a, b, c, 0, 0, 0);
}
using gptr_t = const __attribute__((address_space(1))) unsigned int*;
using lptr_t = __attribute__((address_space(3))) unsigned int*;
__device__ __forceinline__ void lds16(const void* g, void* l) {
    __builtin_amdgcn_global_load_lds((gptr_t)g, (lptr_t)l, 16, 0, 0);
}

#define ATT_SCALE 0.1275758218522532f   // log2(e) / sqrt(128)

// ---------- 1. convert x f32 -> bf16 ----------
__global__ __launch_bounds__(256) void cvt_x(const float* __restrict__ x, u16* __restrict__ xb) {
    size_t i = ((size_t)blockIdx.x * 256 + threadIdx.x) * 4;
    float4 v = *(const float4*)&x[i];
    ushort4 r; r.x = f2bf(v.x); r.y = f2bf(v.y); r.z = f2bf(v.z); r.w = f2bf(v.w);
    *(ushort4*)&xb[i] = r;
}

// ---------- 2. transpose+convert weight f32 [2048][2048] -> bf16 [n][k] ----------
__global__ __launch_bounds__(256) void transpose_w(const float* __restrict__ in, u16* __restrict__ out) {
    __shared__ float t[64][65];
    int k0 = blockIdx.x * 64, n0 = blockIdx.y * 64;
    int tx = threadIdx.x, ty = threadIdx.y;   // (64,4)
#pragma unroll
    for (int i = 0; i < 16; ++i) {
        int r = i * 4 + ty;
        t[r][tx] = in[(size_t)(k0 + r) * 2048 + n0 + tx];
    }
    __syncthreads();
#pragma unroll
    for (int i = 0; i < 16; ++i) {
        int r = i * 4 + ty;
        out[(size_t)(n0 + r) * 2048 + k0 + tx] = f2bf(t[tx][r]);
    }
}

// ---------- 3. main GEMM (A[m][k] bf16, B^T[n][k] bf16), 128x128 tile, BK=64 ----------
template <int MODE>
__global__ __launch_bounds__(256) void gemm_bt(const u16* __restrict__ A, const u16* __restrict__ B,
                                               u16* __restrict__ Qo, u16* __restrict__ Ko, u16* __restrict__ Vo,
                                               float* __restrict__ Co) {
    __shared__ __align__(16) u16 As[128 * 64];
    __shared__ __align__(16) u16 Bs[128 * 64];
    const int m0 = blockIdx.y << 7;
    const int n0 = blockIdx.x << 7;
    const int tid = threadIdx.x;
    const int w = tid >> 6, lane = tid & 63;
    const int wm = w >> 1, wn = w & 1;
    const int m16 = lane & 15, q4 = lane >> 4;

    floatx4 acc[4][4];
#pragma unroll
    for (int r = 0; r < 4; ++r)
#pragma unroll
        for (int c = 0; c < 4; ++c) acc[r][c] = (floatx4)0.0f;

    const u16* Abase = A + (size_t)(m0 + w * 32 + (lane >> 3)) * 2048 + (lane & 7) * 8;
    const u16* Bbase = B + (size_t)(n0 + w * 32 + (lane >> 3)) * 2048 + (lane & 7) * 8;
    u16* lA = As + (w * 32) * 64;
    u16* lB = Bs + (w * 32) * 64;

    for (int kt = 0; kt < 32; ++kt) {
        __syncthreads();
        const u16* ga = Abase + kt * 64;
        const u16* gb = Bbase + kt * 64;
#pragma unroll
        for (int t = 0; t < 4; ++t) {
            lds16(ga + (size_t)t * 8 * 2048, lA + t * 8 * 64);
            lds16(gb + (size_t)t * 8 * 2048, lB + t * 8 * 64);
        }
        __syncthreads();
#pragma unroll
        for (int kk = 0; kk < 2; ++kk) {
            bf16x8 af[4], bfr[4];
#pragma unroll
            for (int r = 0; r < 4; ++r)
                af[r] = *(const bf16x8*)&As[(wm * 64 + r * 16 + m16) * 64 + kk * 32 + q4 * 8];
#pragma unroll
            for (int c = 0; c < 4; ++c)
                bfr[c] = *(const bf16x8*)&Bs[(wn * 64 + c * 16 + m16) * 64 + kk * 32 + q4 * 8];
#pragma unroll
            for (int r = 0; r < 4; ++r)
#pragma unroll
                for (int c = 0; c < 4; ++c)
                    acc[r][c] = mfma16(af[r], bfr[c], acc[r][c]);
        }
    }

    if (MODE == 0) {
        const int which = n0 >> 11;
        const int h = (n0 >> 7) & 15;
        u16* dst = (which == 0) ? Qo : ((which == 1) ? Ko : Vo);
#pragma unroll
        for (int r = 0; r < 4; ++r) {
#pragma unroll
            for (int c = 0; c < 4; ++c) {
                int d = wn * 64 + c * 16 + m16;
                int mbase = m0 + wm * 64 + r * 16 + q4 * 4;
#pragma unroll
                for (int i = 0; i < 4; ++i) {
                    int mm = mbase + i;
                    int b = mm >> 11, s = mm & 2047;
                    dst[((size_t)((b * 16 + h) * 2048 + s) << 7) + d] = f2bf(acc[r][c][i]);
                }
            }
        }
    } else {
#pragma unroll
        for (int r = 0; r < 4; ++r) {
#pragma unroll
            for (int c = 0; c < 4; ++c) {
                int n = n0 + wn * 64 + c * 16 + m16;
                int mbase = m0 + wm * 64 + r * 16 + q4 * 4;
#pragma unroll
                for (int i = 0; i < 4; ++i)
                    Co[(size_t)(mbase + i) * 2048 + n] = acc[r][c][i];
            }
        }
    }
}

// ---------- 4. RoPE in place on Q,K; Q gets pre-scaled by log2(e)/sqrt(HD) ----------
__global__ __launch_bounds__(256) void rope_qk(u16* __restrict__ Q, u16* __restrict__ K,
                                               const float* __restrict__ cosb, const float* __restrict__ sinb) {
    int t = blockIdx.x * 256 + threadIdx.x;   // B*H*S*64
    int d = t & 63;
    int row = t >> 6;
    int s = row & 2047;
    float c = cosb[s * 64 + d], sn = sinb[s * 64 + d];
    size_t base = (size_t)row * 128;
    float q0 = bf2f(Q[base + d]), q1 = bf2f(Q[base + 64 + d]);
    Q[base + d]      = f2bf((q0 * c - q1 * sn) * ATT_SCALE);
    Q[base + 64 + d] = f2bf((q1 * c + q0 * sn) * ATT_SCALE);
    float k0 = bf2f(K[base + d]), k1 = bf2f(K[base + 64 + d]);
    K[base + d]      = f2bf(k0 * c - k1 * sn);
    K[base + 64 + d] = f2bf(k1 * c + k0 * sn);
}

// ---------- 5. transpose V [b,h][2048][128] -> V^T [b,h][128][2048] ----------
__global__ __launch_bounds__(256) void transpose_v(const u16* __restrict__ V, u16* __restrict__ VT) {
    __shared__ u16 t[64][65];
    int bh = blockIdx.z;
    const u16* in = V + (size_t)bh * 2048 * 128;
    u16* out = VT + (size_t)bh * 128 * 2048;
    int s0 = blockIdx.x * 64, d0 = blockIdx.y * 64;
    int tx = threadIdx.x, ty = threadIdx.y;
#pragma unroll
    for (int i = 0; i < 16; ++i) {
        int r = i * 4 + ty;
        t[r][tx] = in[(size_t)(s0 + r) * 128 + d0 + tx];
    }
    __syncthreads();
#pragma unroll
    for (int i = 0; i < 16; ++i) {
        int r = i * 4 + ty;
        out[(size_t)(d0 + r) * 2048 + s0 + tx] = t[tx][r];
    }
}

// ---------- 6. flash attention v2: 512 thr / 8 waves, 16 q-rows per wave ----------
// S^T = K Q^T so softmax is lane-local; heavy-first block order.
// Q pre-scaled by log2(e)/sqrt(128). Q,K: [b,h,s,128]; VT: [b,h,128,s]; AO: [b,s,h*128+d]
__global__ __launch_bounds__(512, 4) void attn_kernel(const u16* __restrict__ Q, const u16* __restrict__ K,
                                                      const u16* __restrict__ VT, u16* __restrict__ AO) {
    __shared__ __align__(16) u16 ks[64 * 136];    // K-tile  [k 64][d 128+pad]
    __shared__ __align__(16) u16 vts[128 * 72];   // V^T     [d 128][s 64+pad]
    __shared__ __align__(16) u16 ps[128 * 72];    // P       [q 128][k 64+pad]
    const int bx = blockIdx.x;
    const int iq = 15 - (bx >> 6);                // heavy-first
    const int bh = bx & 63;
    const int b = bh >> 4, h = bh & 15;
    const u16* Qg = Q  + (size_t)bh * (2048 * 128);
    const u16* Kg = K  + (size_t)bh * (2048 * 128);
    const u16* Vg = VT + (size_t)bh * (128 * 2048);
    const int tid = threadIdx.x, w = tid >> 6, lane = tid & 63;
    const int m16 = lane & 15, q4 = lane >> 4;

    // wave w owns q-rows [iq*128 + w*16, +16)
    const int qrow = iq * 128 + w * 16;
    bf16x8 qf[4];
#pragma unroll
    for (int kk = 0; kk < 4; ++kk)
        qf[kk] = *(const bf16x8*)&Qg[(size_t)(qrow + m16) * 128 + kk * 32 + q4 * 8];

    floatx4 o[8];
#pragma unroll
    for (int c = 0; c < 8; ++c) o[c] = (floatx4)0.0f;
    float mrow = -1e30f, lrow = 0.0f;             // per-lane state for q = qrow + m16

    const int jn = 2 * iq + 2;
    for (int j = 0; j < jn; ++j) {
        __syncthreads();                          // prev iter done with ks/vts
        // stage K tile (64x128) and V^T tile (128x64), 2 uint4 each per thread
        {
            int u0 = tid, u1 = tid + 512;
            int r0 = u0 >> 4, c0 = u0 & 15, r1 = u1 >> 4, c1 = u1 & 15;
            uint4 ka = *(const uint4*)&Kg[(size_t)(j * 64 + r0) * 128 + c0 * 8];
            uint4 kb2 = *(const uint4*)&Kg[(size_t)(j * 64 + r1) * 128 + c1 * 8];
            int vr0 = tid >> 3, vc0 = tid & 7, vr1 = (tid + 512) >> 3, vc1 = tid & 7;
            uint4 va = *(const uint4*)&Vg[(size_t)vr0 * 2048 + j * 64 + vc0 * 8];
            uint4 vb2 = *(const uint4*)&Vg[(size_t)vr1 * 2048 + j * 64 + vc1 * 8];
            *(uint4*)&ks[r0 * 136 + c0 * 8] = ka;
            *(uint4*)&ks[r1 * 136 + c1 * 8] = kb2;
            *(uint4*)&vts[vr0 * 72 + vc0 * 8] = va;
            *(uint4*)&vts[vr1 * 72 + vc1 * 8] = vb2;
        }
        __syncthreads();

        // S^T = K Q^T : rows k (4 tiles of 16), cols q (16). A=K frag, B=Q frag.
        floatx4 sacc[4];
#pragma unroll
        for (int r = 0; r < 4; ++r) sacc[r] = (floatx4)0.0f;
#pragma unroll
        for (int kk = 0; kk < 4; ++kk) {
            bf16x8 kb[4];
#pragma unroll
            for (int r = 0; r < 4; ++r)
                kb[r] = *(const bf16x8*)&ks[(r * 16 + m16) * 136 + kk * 32 + q4 * 8];
#pragma unroll
            for (int r = 0; r < 4; ++r)
                sacc[r] = mfma16(kb[r], qf[kk], sacc[r]);
        }

        // mask: lane holds S^T[k = j*64 + r*16 + q4*4 + i][q = qrow + m16]
        if (j >= 2 * iq) {
            const int qg = qrow + m16;
#pragma unroll
            for (int r = 0; r < 4; ++r)
#pragma unroll
                for (int i = 0; i < 4; ++i) {
                    int kg = j * 64 + r * 16 + q4 * 4 + i;
                    if (kg > qg) sacc[r][i] = -1e30f;
                }
        }

        // lane-local max over 16 values, then butterfly over q4 group (xor 16, 32)
        float pmax = -1e30f;
#pragma unroll
        for (int r = 0; r < 4; ++r)
#pragma unroll
            for (int i = 0; i < 4; ++i) pmax = fmaxf(pmax, sacc[r][i]);
        pmax = fmaxf(pmax, __shfl_xor(pmax, 16));
        pmax = fmaxf(pmax, __shfl_xor(pmax, 32));
        float mnew = fmaxf(mrow, pmax);
        float alpha = __builtin_amdgcn_exp2f(mrow - mnew);
        mrow = mnew;

        // P = exp2(S - m), write wave-private rows of ps as packed b64
        float psum = 0.0f;
#pragma unroll
        for (int r = 0; r < 4; ++r) {
            float p0 = __builtin_amdgcn_exp2f(sacc[r][0] - mnew);
            float p1 = __builtin_amdgcn_exp2f(sacc[r][1] - mnew);
            float p2 = __builtin_amdgcn_exp2f(sacc[r][2] - mnew);
            float p3 = __builtin_amdgcn_exp2f(sacc[r][3] - mnew);
            psum += (p0 + p1) + (p2 + p3);
            ushort4 pk; pk.x = f2bf(p0); pk.y = f2bf(p1); pk.z = f2bf(p2); pk.w = f2bf(p3);
            *(ushort4*)&ps[(w * 16 + m16) * 72 + r * 16 + q4 * 4] = pk;
        }
        psum += __shfl_xor(psum, 16);
        psum += __shfl_xor(psum, 32);
        lrow = lrow * alpha + psum;

        // rescale O: alpha is per-q; O rows are q = q4*4+i -> broadcast via shfl
        float abc[4];
#pragma unroll
        for (int i = 0; i < 4; ++i) abc[i] = __shfl(alpha, q4 * 4 + i);
#pragma unroll
        for (int c = 0; c < 8; ++c)
#pragma unroll
            for (int i = 0; i < 4; ++i) o[c][i] *= abc[i];

        // O += P V  (A = P[q][k] own rows, B = V^T[d][k])
#pragma unroll
        for (int kk = 0; kk < 2; ++kk) {
            bf16x8 pa = *(const bf16x8*)&ps[(w * 16 + m16) * 72 + kk * 32 + q4 * 8];
            bf16x8 vb[8];
#pragma unroll
            for (int c = 0; c < 8; ++c)
                vb[c] = *(const bf16x8*)&vts[(c * 16 + m16) * 72 + kk * 32 + q4 * 8];
#pragma unroll
            for (int c = 0; c < 8; ++c)
                o[c] = mfma16(pa, vb[c], o[c]);
        }
    }

    // epilogue: O row = q4*4+i, col d = c*16+m16; l lives at lane m16=q -> shfl
    float linv = __builtin_amdgcn_rcpf(lrow);
    float li[4];
#pragma unroll
    for (int i = 0; i < 4; ++i) li[i] = __shfl(linv, q4 * 4 + i);
#pragma unroll
    for (int c = 0; c < 8; ++c)
#pragma unroll
        for (int i = 0; i < 4; ++i) {
            int s = qrow + q4 * 4 + i;
            int d = c * 16 + m16;
            AO[((size_t)(b * 2048 + s)) * 2048 + h * 128 + d] = f2bf(o[c][i] * li[i]);
        }
}

// ---------- launch ----------
extern "C" void kernel_launch(void* const* d_in, const int* in_sizes, int n_in,
                              void* d_out, int out_size, void* d_ws, size_t ws_size,
                              hipStream_t stream) {
    const float* x    = (const float*)d_in[0];
    const float* wq   = (const float*)d_in[1];
    const float* wk   = (const float*)d_in[2];
    const float* wv   = (const float*)d_in[3];
    const float* wo   = (const float*)d_in[4];
    const float* cosb = (const float*)d_in[5];
    const float* sinb = (const float*)d_in[6];
    float* out = (float*)d_out;

    char* ws = (char*)d_ws;
    u16* xb    = (u16*)(ws);
    u16* AO    = xb;                                  // alias: xb dead after QKV GEMM
    u16* wqkvb = (u16*)(ws + 33554432);
    u16* wob   = (u16*)(ws + 58720256);
    u16* Qb    = (u16*)(ws + 67108864);
    u16* Kb    = (u16*)(ws + 100663296);
    u16* Vb    = (u16*)(ws + 134217728);
    u16* Vtb   = (u16*)(ws + 167772160);

    cvt_x<<<16384, 256, 0, stream>>>(x, xb);
    transpose_w<<<dim3(32, 32), dim3(64, 4), 0, stream>>>(wq, wqkvb);
    transpose_w<<<dim3(32, 32), dim3(64, 4), 0, stream>>>(wk, wqkvb + (size_t)2048 * 2048);
    transpose_w<<<dim3(32, 32), dim3(64, 4), 0, stream>>>(wv, wqkvb + (size_t)2 * 2048 * 2048);
    transpose_w<<<dim3(32, 32), dim3(64, 4), 0, stream>>>(wo, wob);

    gemm_bt<0><<<dim3(48, 64), 256, 0, stream>>>(xb, wqkvb, Qb, Kb, Vb, nullptr);
    rope_qk<<<32768, 256, 0, stream>>>(Qb, Kb, cosb, sinb);
    transpose_v<<<dim3(32, 2, 64), dim3(64, 4), 0, stream>>>(Vb, Vtb);
    attn_kernel<<<1024, 512, 0, stream>>>(Qb, Kb, Vtb, AO);
    gemm_bt<1><<<dim3(16, 64), 256, 0, stream>>>(AO, wob, nullptr, nullptr, nullptr, out);
}